// Round 11
// baseline (43.851 us; speedup 1.0000x reference)
//
#include <hip/hip_runtime.h>

#define BATCH 64
#define TLEN  2048
#define DDIM  256
#define ADIM  128
#define TM    64          // t-rows per tile (16 per wave)
#define TILES 4           // tiles per block
#define EPSC  1e-7f

typedef __bf16 bf16x8 __attribute__((ext_vector_type(8)));
typedef float  f32x4  __attribute__((ext_vector_type(4)));
typedef int    i32x4  __attribute__((ext_vector_type(4)));

// DPP-based add of a lane-permuted copy (VALU pipe, not LDS)
template <int CTRL>
__device__ __forceinline__ float dpp_add(float v) {
    int vi = __builtin_bit_cast(int, v);
    int sw = __builtin_amdgcn_update_dpp(vi, vi, CTRL, 0xF, 0xF, false);
    return v + __builtin_bit_cast(float, sw);
}

// ws layout:
//   [0,      65536)  : Wf  bf16[32768]  (B-fragment-ordered W)
//   [65536, 131072)  : N   f32[16384]   (unnormalized numerator, per b,d)
//   [131072,131328)  : s   f32[64]      (unnormalized denominator, per b)

__global__ __launch_bounds__(256) void prep_kernel(const float* __restrict__ W,
                                                   __bf16* __restrict__ Wf,
                                                   float* __restrict__ N,
                                                   float* __restrict__ s) {
    int idx = blockIdx.x * 256 + threadIdx.x;   // [0, 32768)
    int j  = idx & 7;
    int l  = (idx >> 3) & 63;
    int nt = (idx >> 9) & 7;
    int kt = idx >> 12;
    int k = kt * 32 + (l >> 4) * 8 + j;         // K index into D
    int n = nt * 16 + (l & 15);                 // N index into A
    Wf[idx] = (__bf16)W[k * ADIM + n];
    if (idx < BATCH * DDIM) N[idx] = 0.0f;
    if (idx >= BATCH * DDIM && idx < BATCH * DDIM + BATCH) s[idx - BATCH * DDIM] = 0.0f;
}

// Zero per-tile barriers: each wave owns 16 rows end-to-end (load -> GEMM over
// all 128 cols -> logits -> exp -> pool from its own registers). W fragments
// live in LDS (staged once), so the K-loop issues NO vmem except the next-tile
// x prefetch -> vmcnt waits never stall mid-tile. Waves slip freely.
__global__ __launch_bounds__(256, 2) void attn_main(const float* __restrict__ x,
                                                    const float* __restrict__ bias,
                                                    const float* __restrict__ u,
                                                    const __bf16* __restrict__ Wf,
                                                    float* __restrict__ N,
                                                    float* __restrict__ s) {
    __shared__ char  wflds[ADIM * DDIM * 2];   // 64 KB: all 64 B-fragments
    __shared__ float fpart[4][4][64];          // epilogue pooling partials (4 KB)
    __shared__ float wlds[4][16];              // per-wave exp-weights of its 16 rows
    __shared__ float ssum_lds[4];

    const int b    = blockIdx.x >> 3;            // 8 blocks per batch
    const int t00  = (blockIdx.x & 7) * (TILES * TM);
    const int tid  = threadIdx.x;
    const int wave = tid >> 6;
    const int lane = tid & 63;
    const int lm   = lane & 15;                  // A-frag row / C col-within-tile
    const int lk   = lane >> 4;                  // A-frag k-block / C row-quad
    const int row  = wave * 16 + lm;             // the row this thread owns

    // ---- stage Wf into LDS once (identity copy, coalesced 16B) ----
    {
        const i32x4* src = (const i32x4*)Wf;
        i32x4*       dst = (i32x4*)wflds;
#pragma unroll
        for (int i = 0; i < 16; ++i) dst[i * 256 + tid] = src[i * 256 + tid];
    }
    __syncthreads();   // only barrier before epilogue

    float bias_r[8], u_r[8];
#pragma unroll
    for (int nt = 0; nt < 8; ++nt) {
        bias_r[nt] = bias[nt * 16 + lm];
        u_r[nt]    = u[nt * 16 + lm];
    }

    float vacc[8][8];
#pragma unroll
    for (int kt = 0; kt < 8; ++kt)
#pragma unroll
        for (int i = 0; i < 8; ++i) vacc[kt][i] = 0.f;
    float sreg = 0.f;

    const float* xbase = x + ((size_t)(b * TLEN + t00 + row)) * DDIM;

    // ---- prologue: load tile 0 (own row, f32, A-frag layout) ----
    f32x4 fa[8], fb[8];
#pragma unroll
    for (int kt = 0; kt < 8; ++kt) {
        fa[kt] = *(const f32x4*)(xbase + kt * 32 + lk * 8);
        fb[kt] = *(const f32x4*)(xbase + kt * 32 + lk * 8 + 4);
    }

    for (int it = 0; it < TILES; ++it) {
        // ---- cvt own row to bf16 A-fragments (fa/fb dead after this) ----
        bf16x8 abf[8];
#pragma unroll
        for (int kt = 0; kt < 8; ++kt) {
#pragma unroll
            for (int i = 0; i < 4; ++i) { abf[kt][i] = (__bf16)fa[kt][i]; abf[kt][4 + i] = (__bf16)fb[kt][i]; }
        }

        // ---- issue next tile's x loads; they have the whole tile to land ----
        if (it + 1 < TILES) {
            const float* xn = xbase + (size_t)(it + 1) * TM * DDIM;
#pragma unroll
            for (int kt = 0; kt < 8; ++kt) {
                fa[kt] = *(const f32x4*)(xn + kt * 32 + lk * 8);
                fb[kt] = *(const f32x4*)(xn + kt * 32 + lk * 8 + 4);
            }
        }

        // ---- GEMM: own 16 rows x all 128 cols; W frags from LDS (no vmcnt) ----
        f32x4 acc[8];
#pragma unroll
        for (int nt = 0; nt < 8; ++nt) acc[nt] = (f32x4){0.f, 0.f, 0.f, 0.f};
#pragma unroll
        for (int kt = 0; kt < 8; ++kt) {
#pragma unroll
            for (int nt = 0; nt < 8; ++nt) {
                bf16x8 wf = *(const bf16x8*)(wflds + ((size_t)((kt * 8 + nt) * 64 + lane)) * 16);
                acc[nt] = __builtin_amdgcn_mfma_f32_16x16x32_bf16(abf[kt], wf, acc[nt], 0, 0, 0);
            }
        }

        // ---- logits: tanh-dot-u, 16-lane DPP reduce; exp at lm==0 lanes ----
#pragma unroll
        for (int reg = 0; reg < 4; ++reg) {
            float p = 0.f;
#pragma unroll
            for (int nt = 0; nt < 8; ++nt) {
                float lg = acc[nt][reg] + bias_r[nt];
                float e  = __expf(2.0f * lg);
                float th = 1.0f - 2.0f * __builtin_amdgcn_rcpf(e + 1.0f);  // tanh, inf-safe
                p += th * u_r[nt];
            }
            p = dpp_add<0xB1>(p);   // xor 1
            p = dpp_add<0x4E>(p);   // xor 2
            p = dpp_add<0x141>(p);  // row_half_mirror
            p = dpp_add<0x140>(p);  // row_mirror -> full 16-lane sum
            if (lm == 0) {
                float wv = __expf(p);
                wlds[wave][lk * 4 + reg] = wv;   // row lk*4+reg of this wave
                sreg += wv;
            }
        }
        // wave-local visibility of wlds (no cross-wave barrier needed)
        asm volatile("s_waitcnt lgkmcnt(0)" ::: "memory");

        // ---- pool: own row from registers, weight via LDS broadcast ----
        const float w_own = wlds[wave][lm];
#pragma unroll
        for (int kt = 0; kt < 8; ++kt)
#pragma unroll
            for (int i = 0; i < 8; ++i)
                vacc[kt][i] += (float)abf[kt][i] * w_own;
    }

    // ---- epilogue: reduce vacc across the 16 lm-lanes (same lk = same d set) ----
#pragma unroll
    for (int kt = 0; kt < 8; ++kt) {
#pragma unroll
        for (int i = 0; i < 8; ++i) {
            float v = vacc[kt][i];
            v = dpp_add<0xB1>(v);
            v = dpp_add<0x4E>(v);
            v = dpp_add<0x141>(v);
            v = dpp_add<0x140>(v);
            vacc[kt][i] = v;   // full sum at lm==0 of each 16-lane row-group
        }
    }
    if (lm == 0) {
#pragma unroll
        for (int kt = 0; kt < 8; ++kt) {
            *(f32x4*)&fpart[wave][lk][kt * 8 + 0] = (f32x4){vacc[kt][0], vacc[kt][1], vacc[kt][2], vacc[kt][3]};
            *(f32x4*)&fpart[wave][lk][kt * 8 + 4] = (f32x4){vacc[kt][4], vacc[kt][5], vacc[kt][6], vacc[kt][7]};
        }
    }

    // ---- epilogue: denominator (nonzero only at lm==0 lanes) ----
    float ss = sreg;
#pragma unroll
    for (int off = 1; off < 64; off <<= 1) ss += __shfl_xor(ss, off);
    if (lane == 0) ssum_lds[wave] = ss;

    __syncthreads();
    if (tid == 0)
        atomicAdd(&s[b], ssum_lds[0] + ssum_lds[1] + ssum_lds[2] + ssum_lds[3]);

    // d = tid: kt = d>>5, lk = (d>>3)&3, j = d&7
    {
        const int kt = tid >> 5, lkq = (tid >> 3) & 3, j = tid & 7;
        float r = fpart[0][lkq][kt * 8 + j] + fpart[1][lkq][kt * 8 + j]
                + fpart[2][lkq][kt * 8 + j] + fpart[3][lkq][kt * 8 + j];
        atomicAdd(&N[b * DDIM + tid], r);
    }
}

__global__ __launch_bounds__(256) void finalize_kernel(const float* __restrict__ N,
                                                       const float* __restrict__ s,
                                                       float* __restrict__ out) {
    int idx = blockIdx.x * 256 + threadIdx.x;   // [0, 16384)
    out[idx] = N[idx] / (s[idx >> 8] + EPSC);
}

extern "C" void kernel_launch(void* const* d_in, const int* in_sizes, int n_in,
                              void* d_out, int out_size, void* d_ws, size_t ws_size,
                              hipStream_t stream) {
    const float* x    = (const float*)d_in[0];
    const float* W    = (const float*)d_in[1];
    const float* bias = (const float*)d_in[2];
    const float* u    = (const float*)d_in[3];
    float* out = (float*)d_out;

    char* ws = (char*)d_ws;
    __bf16* Wf = (__bf16*)ws;
    float*  N  = (float*)(ws + 65536);
    float*  s  = (float*)(ws + 131072);

    prep_kernel<<<128, 256, 0, stream>>>(W, Wf, N, s);
    attn_main<<<BATCH * TLEN / (TILES * TM), 256, 0, stream>>>(x, bias, u, Wf, N, s);
    finalize_kernel<<<(BATCH * DDIM) / 256, 256, 0, stream>>>(N, s, out);
}